// Round 1
// baseline (1090.176 us; speedup 1.0000x reference)
//
#include <hip/hip_runtime.h>

#define DHID 64
#define DIN 6
#define SDEG 16

static __device__ __forceinline__ float rlane(float v, int k) {
  return __uint_as_float(__builtin_amdgcn_readlane(__float_as_uint(v), k));
}

// ---- CSR build -------------------------------------------------------------

__global__ void k_count(const int* __restrict__ dst, int* __restrict__ deg, int E) {
  int e = blockIdx.x * blockDim.x + threadIdx.x;
  if (e < E) atomicAdd(&deg[dst[e]], 1);
}

__global__ void k_scan(const int* __restrict__ deg, int* __restrict__ rowptr,
                       int* __restrict__ cursor, int* __restrict__ gtotal, int N) {
  int i = blockIdx.x * blockDim.x + threadIdx.x;
  int lane = threadIdx.x & 63;
  int d = (i < N) ? deg[i] : 0;
  int v = d;
#pragma unroll
  for (int off = 1; off < 64; off <<= 1) {
    int t = __shfl_up(v, off);
    if (lane >= off) v += t;
  }
  int total = __shfl(v, 63);
  int base = 0;
  if (lane == 63) base = atomicAdd(gtotal, total);
  base = __shfl(base, 63);
  int start = base + v - d;  // exclusive within wave + global base
  if (i < N) { rowptr[i] = start; cursor[i] = start; }
}

__global__ void k_fill(const int* __restrict__ src, const int* __restrict__ dst,
                       int* __restrict__ cursor, int* __restrict__ col,
                       const int* __restrict__ selfp, int* __restrict__ selfcnt,
                       int* __restrict__ selflist, int E) {
  int e = blockIdx.x * blockDim.x + threadIdx.x;
  if (e >= E) return;
  int s = src[e];
  int d = dst[e];
  int pos = atomicAdd(&cursor[d], 1);
  col[pos] = s;
  if (s == *selfp) {
    int i = atomicAdd(selfcnt, 1);
    if (i < SDEG) selflist[i] = e;
  }
}

// ---- Layer 0: x[N,6] -> h[N,64], ReLU --------------------------------------

__global__ __launch_bounds__(256, 2) void k_layer0(
    const float* __restrict__ x, const int* __restrict__ rowptr,
    const int* __restrict__ deg, const int* __restrict__ col,
    const float* __restrict__ W0l, const float* __restrict__ W0r,
    const float* __restrict__ b0, float* __restrict__ hout, int N) {
  int lane = threadIdx.x & 63;
  int wid = blockIdx.x * (blockDim.x >> 6) + (threadIdx.x >> 6);
  int nw = gridDim.x * (blockDim.x >> 6);
  float w0l[DIN], w0r[DIN];
#pragma unroll
  for (int k = 0; k < DIN; ++k) {
    w0l[k] = W0l[k * DHID + lane];
    w0r[k] = W0r[k * DHID + lane];
  }
  float bv = b0[lane];
  int d6 = (lane < DIN) ? lane : 0;
  for (int node = wid; node < N; node += nw) {
    int start = rowptr[node], cnt = deg[node];
    float acc = 0.f;
    for (int e = 0; e < cnt; ++e) {
      int s = col[start + e];          // wave-uniform
      acc += x[s * DIN + d6];          // lanes >=6 read dup of elem 0 (unused)
    }
    float mean = acc / fmaxf((float)cnt, 1.0f);
    float xi = x[node * DIN + d6];
    float out = bv;
#pragma unroll
    for (int k = 0; k < DIN; ++k) {
      out = fmaf(rlane(mean, k), w0l[k], out);
      out = fmaf(rlane(xi, k), w0r[k], out);
    }
    hout[node * DHID + lane] = fmaxf(out, 0.f);
  }
}

// ---- Layers 1..3: h[N,64] -> h[N,64] ---------------------------------------

__global__ __launch_bounds__(256, 2) void k_layer(
    const float* __restrict__ hin, const int* __restrict__ rowptr,
    const int* __restrict__ deg, const int* __restrict__ col,
    const float* __restrict__ Wl, const float* __restrict__ Wr,
    const float* __restrict__ b, float* __restrict__ hout, int N, int do_relu) {
  int lane = threadIdx.x & 63;
  int wid = blockIdx.x * (blockDim.x >> 6) + (threadIdx.x >> 6);
  int nw = gridDim.x * (blockDim.x >> 6);
  // lane d holds column d of Wl and Wr in registers (128 VGPRs)
  float wl[DHID], wr[DHID];
#pragma unroll
  for (int k = 0; k < DHID; ++k) {
    wl[k] = Wl[k * DHID + lane];
    wr[k] = Wr[k * DHID + lane];
  }
  float bv = b[lane];
  for (int node = wid; node < N; node += nw) {
    int start = rowptr[node], cnt = deg[node];
    float acc = 0.f;
    int e = 0;
    for (; e + 4 <= cnt; e += 4) {   // 4 outstanding gathers for MLP
      int s0 = col[start + e + 0];
      int s1 = col[start + e + 1];
      int s2 = col[start + e + 2];
      int s3 = col[start + e + 3];
      float a0 = hin[s0 * DHID + lane];
      float a1 = hin[s1 * DHID + lane];
      float a2 = hin[s2 * DHID + lane];
      float a3 = hin[s3 * DHID + lane];
      acc += (a0 + a1) + (a2 + a3);
    }
    for (; e < cnt; ++e) acc += hin[col[start + e] * DHID + lane];
    float mean = acc / fmaxf((float)cnt, 1.0f);
    float hi = hin[node * DHID + lane];
    float out = bv;
#pragma unroll
    for (int k = 0; k < DHID; ++k) {
      out = fmaf(rlane(mean, k), wl[k], out);
      out = fmaf(rlane(hi, k), wr[k], out);
    }
    hout[node * DHID + lane] = do_relu ? fmaxf(out, 0.f) : out;
  }
}

// ---- Head: sort self-edges, logits, value, neighbors -----------------------

__global__ void k_head(const float* __restrict__ h, const int* __restrict__ dst,
                       const int* __restrict__ selfp, const int* __restrict__ selflist,
                       const int* __restrict__ selfcnt, const float* __restrict__ Wlog,
                       const float* __restrict__ blog, const float* __restrict__ Wval,
                       const float* __restrict__ bval, float* __restrict__ out) {
  __shared__ int sorted[SDEG];
  __shared__ int nbr[SDEG];
  int t = threadIdx.x;  // block = 64 threads (1 wave)
  int self = *selfp;
  if (t == 0) {
    int c = *selfcnt;
    if (c > SDEG) c = SDEG;
    int tmp[SDEG];
    for (int j = 0; j < SDEG; ++j) tmp[j] = (j < c) ? selflist[j] : 0;  // fill_value=0
    for (int a = 1; a < c; ++a) {  // insertion sort ascending (nonzero order)
      int v = tmp[a];
      int bq = a - 1;
      while (bq >= 0 && tmp[bq] > v) { tmp[bq + 1] = tmp[bq]; --bq; }
      tmp[bq + 1] = v;
    }
    for (int j = 0; j < SDEG; ++j) sorted[j] = tmp[j];
  }
  __syncthreads();
  if (t < SDEG) nbr[t] = dst[sorted[t]];
  __syncthreads();

  // logits: 16 rows x 128-dot; 4 lanes per row, 32 elems each
  int r = t >> 2, p = t & 3;
  float part = 0.f;
  for (int k = p * 32; k < p * 32 + 32; ++k) {
    float ev = (k < DHID) ? h[self * DHID + k] : h[nbr[r] * DHID + (k - DHID)];
    part += ev * Wlog[k];
  }
  part += __shfl_xor(part, 1);
  part += __shfl_xor(part, 2);
  if (p == 0) out[r] = part + blog[0];

  // value: self_emb . Wval
  float pv = h[self * DHID + t] * Wval[t];
#pragma unroll
  for (int off = 32; off; off >>= 1) pv += __shfl_xor(pv, off);
  if (t == 0) out[SDEG] = pv + bval[0];

  // neighbors as float
  if (t < SDEG) out[SDEG + 1 + t] = (float)nbr[t];
}

// ---- launcher --------------------------------------------------------------

extern "C" void kernel_launch(void* const* d_in, const int* in_sizes, int n_in,
                              void* d_out, int out_size, void* d_ws, size_t ws_size,
                              hipStream_t stream) {
  const float* x    = (const float*)d_in[0];
  const int*   ei   = (const int*)d_in[1];
  const int*   selfp= (const int*)d_in[2];
  const float* W0l  = (const float*)d_in[3];
  const float* W0r  = (const float*)d_in[4];
  const float* b0   = (const float*)d_in[5];
  const float* Wl   = (const float*)d_in[6];
  const float* Wr   = (const float*)d_in[7];
  const float* bb   = (const float*)d_in[8];
  const float* Wlog = (const float*)d_in[9];
  const float* blog = (const float*)d_in[10];
  const float* Wval = (const float*)d_in[11];
  const float* bval = (const float*)d_in[12];
  float* out = (float*)d_out;

  int N = in_sizes[0] / DIN;
  int E = in_sizes[1] / 2;
  const int* src = ei;
  const int* dstp = ei + E;

  size_t off = 0;
  auto alloc = [&](size_t bytes) {
    void* p = (char*)d_ws + off;
    off += (bytes + 255) & ~(size_t)255;
    return p;
  };
  int* meta    = (int*)alloc(64 * 4);           // [0]=gtotal [1]=selfcnt [2..17]=selflist
  int* deg     = (int*)alloc((size_t)N * 4);
  int* rowptr  = (int*)alloc((size_t)N * 4);
  int* cursor  = (int*)alloc((size_t)N * 4);
  int* col     = (int*)alloc((size_t)E * 4);
  float* hA    = (float*)alloc((size_t)N * DHID * 4);
  float* hB    = (float*)alloc((size_t)N * DHID * 4);
  int* gtotal   = meta + 0;
  int* selfcnt  = meta + 1;
  int* selflist = meta + 2;

  hipMemsetAsync(meta, 0, 64 * 4, stream);
  hipMemsetAsync(deg, 0, (size_t)N * 4, stream);

  const int TB = 256;
  k_count<<<(E + TB - 1) / TB, TB, 0, stream>>>(dstp, deg, E);
  k_scan<<<(N + TB - 1) / TB, TB, 0, stream>>>(deg, rowptr, cursor, gtotal, N);
  k_fill<<<(E + TB - 1) / TB, TB, 0, stream>>>(src, dstp, cursor, col, selfp,
                                               selfcnt, selflist, E);

  k_layer0<<<1024, 256, 0, stream>>>(x, rowptr, deg, col, W0l, W0r, b0, hA, N);
  k_layer<<<1024, 256, 0, stream>>>(hA, rowptr, deg, col, Wl + 0 * 4096,
                                    Wr + 0 * 4096, bb + 0 * 64, hB, N, 1);
  k_layer<<<1024, 256, 0, stream>>>(hB, rowptr, deg, col, Wl + 1 * 4096,
                                    Wr + 1 * 4096, bb + 1 * 64, hA, N, 1);
  k_layer<<<1024, 256, 0, stream>>>(hA, rowptr, deg, col, Wl + 2 * 4096,
                                    Wr + 2 * 4096, bb + 2 * 64, hB, N, 0);

  k_head<<<1, 64, 0, stream>>>(hB, dstp, selfp, selflist, selfcnt, Wlog, blog,
                               Wval, bval, out);
}

// Round 3
// 741.410 us; speedup vs baseline: 1.4704x; 1.4704x over previous
//
#include <hip/hip_runtime.h>

#define DHID 64
#define DIN 6
#define SDEG 16

static __device__ __forceinline__ float rlane(float v, int k) {
  return __uint_as_float(__builtin_amdgcn_readlane(__float_as_uint(v), k));
}

// ---- CSR build -------------------------------------------------------------

__global__ void k_count(const int* __restrict__ dst, int* __restrict__ deg, int E) {
  int e = blockIdx.x * blockDim.x + threadIdx.x;
  if (e < E) atomicAdd(&deg[dst[e]], 1);
}

__global__ void k_scan(const int* __restrict__ deg, int* __restrict__ rowptr,
                       int* __restrict__ cursor, int* __restrict__ gtotal, int N) {
  int i = blockIdx.x * blockDim.x + threadIdx.x;
  int lane = threadIdx.x & 63;
  int d = (i < N) ? deg[i] : 0;
  int v = d;
#pragma unroll
  for (int off = 1; off < 64; off <<= 1) {
    int t = __shfl_up(v, off);
    if (lane >= off) v += t;
  }
  int total = __shfl(v, 63);
  int base = 0;
  if (lane == 63) base = atomicAdd(gtotal, total);
  base = __shfl(base, 63);
  int start = base + v - d;  // exclusive within wave + global base
  if (i < N) { rowptr[i] = start; cursor[i] = start; }
}

__global__ void k_fill(const int* __restrict__ src, const int* __restrict__ dst,
                       int* __restrict__ cursor, int* __restrict__ col,
                       const int* __restrict__ selfp, int* __restrict__ selfcnt,
                       int* __restrict__ selflist, int E) {
  int e = blockIdx.x * blockDim.x + threadIdx.x;
  if (e >= E) return;
  int s = src[e];
  int d = dst[e];
  int pos = atomicAdd(&cursor[d], 1);
  col[pos] = s;
  if (s == *selfp) {
    int i = atomicAdd(selfcnt, 1);
    if (i < SDEG) selflist[i] = e;
  }
}

// ---- Layer 0: x[N,6] -> h[N,64], ReLU (fused; weights tiny: 12 VGPR) -------

__global__ __launch_bounds__(256) void k_layer0(
    const float* __restrict__ x, const int* __restrict__ rowptr,
    const int* __restrict__ deg, const int* __restrict__ col,
    const float* __restrict__ W0l, const float* __restrict__ W0r,
    const float* __restrict__ b0, float* __restrict__ hout, int N) {
  int lane = threadIdx.x & 63;
  int wid = blockIdx.x * (blockDim.x >> 6) + (threadIdx.x >> 6);
  int nw = gridDim.x * (blockDim.x >> 6);
  float w0l[DIN], w0r[DIN];
#pragma unroll
  for (int k = 0; k < DIN; ++k) {
    w0l[k] = W0l[k * DHID + lane];
    w0r[k] = W0r[k * DHID + lane];
  }
  float bv = b0[lane];
  int d6 = (lane < DIN) ? lane : 0;
  for (int node = wid; node < N; node += nw) {
    int start = rowptr[node], cnt = deg[node];
    float acc = 0.f;
    for (int e = 0; e < cnt; ++e) {
      int s = col[start + e];          // wave-uniform
      acc += x[s * DIN + d6];          // lanes >=6 read dup (unused)
    }
    float mean = acc / fmaxf((float)cnt, 1.0f);
    float xi = x[node * DIN + d6];
    float out = bv;
#pragma unroll
    for (int k = 0; k < DIN; ++k) {
      out = fmaf(rlane(mean, k), w0l[k], out);
      out = fmaf(rlane(xi, k), w0r[k], out);
    }
    hout[node * DHID + lane] = fmaxf(out, 0.f);
  }
}

// ---- Aggregation: mean[node][lane] = mean of h[src][lane] ------------------
// One wave per node, lane = feature dim. Low VGPR -> high occupancy; 8-deep
// gather unroll for memory-level parallelism.

__global__ __launch_bounds__(256) void k_agg(
    const float* __restrict__ hin, const int* __restrict__ rowptr,
    const int* __restrict__ deg, const int* __restrict__ col,
    float* __restrict__ mean, int N) {
  int lane = threadIdx.x & 63;
  int wid = blockIdx.x * (blockDim.x >> 6) + (threadIdx.x >> 6);
  int nw = gridDim.x * (blockDim.x >> 6);
  for (int node = wid; node < N; node += nw) {
    int start = rowptr[node], cnt = deg[node];
    float a0 = 0.f, a1 = 0.f, a2 = 0.f, a3 = 0.f;
    float a4 = 0.f, a5 = 0.f, a6 = 0.f, a7 = 0.f;
    int e = 0;
    for (; e + 8 <= cnt; e += 8) {
      int s0 = col[start + e + 0], s1 = col[start + e + 1];
      int s2 = col[start + e + 2], s3 = col[start + e + 3];
      int s4 = col[start + e + 4], s5 = col[start + e + 5];
      int s6 = col[start + e + 6], s7 = col[start + e + 7];
      a0 += hin[(size_t)s0 * DHID + lane];
      a1 += hin[(size_t)s1 * DHID + lane];
      a2 += hin[(size_t)s2 * DHID + lane];
      a3 += hin[(size_t)s3 * DHID + lane];
      a4 += hin[(size_t)s4 * DHID + lane];
      a5 += hin[(size_t)s5 * DHID + lane];
      a6 += hin[(size_t)s6 * DHID + lane];
      a7 += hin[(size_t)s7 * DHID + lane];
    }
    for (; e < cnt; ++e) a0 += hin[(size_t)col[start + e] * DHID + lane];
    float s = ((a0 + a1) + (a2 + a3)) + ((a4 + a5) + (a6 + a7));
    mean[(size_t)node * DHID + lane] = s / fmaxf((float)cnt, 1.0f);
  }
}

// ---- Transform: out = mean@Wl + h@Wr + b (optionally ReLU) -----------------
// One node per THREAD, 64 f32 accumulators; W in LDS, read via wave-uniform
// ds_read_b128 broadcasts -> W cost amortized over 64 nodes per wave.

__global__ __launch_bounds__(256) void k_mm(
    const float* __restrict__ mean, const float* __restrict__ hin,
    const float* __restrict__ Wl, const float* __restrict__ Wr,
    const float* __restrict__ b, float* __restrict__ hout, int N, int do_relu) {
  __shared__ float4 sW[2064];  // [0..1023]=Wl rows, [1024..2047]=Wr, [2048..2063]=b
  int t = threadIdx.x;
  const float4* wl4 = (const float4*)Wl;
  const float4* wr4 = (const float4*)Wr;
  for (int i = t; i < 1024; i += 256) sW[i] = wl4[i];
  for (int i = t; i < 1024; i += 256) sW[1024 + i] = wr4[i];
  if (t < 16) sW[2048 + t] = ((const float4*)b)[t];
  __syncthreads();

  int node = blockIdx.x * 256 + t;
  if (node >= N) return;

  const float4* m4 = (const float4*)(mean + (size_t)node * DHID);
  const float4* h4 = (const float4*)(hin + (size_t)node * DHID);

  float acc[DHID];
#pragma unroll
  for (int jc = 0; jc < 16; ++jc) {
    float4 bv = sW[2048 + jc];
    acc[jc * 4 + 0] = bv.x; acc[jc * 4 + 1] = bv.y;
    acc[jc * 4 + 2] = bv.z; acc[jc * 4 + 3] = bv.w;
  }

  for (int kc = 0; kc < 16; ++kc) {   // rolled: 16 iterations
    float4 av = m4[kc];
    float4 hv = h4[kc];
#pragma unroll
    for (int kk = 0; kk < 4; ++kk) {
      int k = kc * 4 + kk;
      float a = (kk == 0) ? av.x : (kk == 1) ? av.y : (kk == 2) ? av.z : av.w;
      float hh = (kk == 0) ? hv.x : (kk == 1) ? hv.y : (kk == 2) ? hv.z : hv.w;
#pragma unroll
      for (int jc = 0; jc < 16; ++jc) {
        float4 wlv = sW[k * 16 + jc];
        float4 wrv = sW[1024 + k * 16 + jc];
        acc[jc * 4 + 0] = fmaf(a, wlv.x, fmaf(hh, wrv.x, acc[jc * 4 + 0]));
        acc[jc * 4 + 1] = fmaf(a, wlv.y, fmaf(hh, wrv.y, acc[jc * 4 + 1]));
        acc[jc * 4 + 2] = fmaf(a, wlv.z, fmaf(hh, wrv.z, acc[jc * 4 + 2]));
        acc[jc * 4 + 3] = fmaf(a, wlv.w, fmaf(hh, wrv.w, acc[jc * 4 + 3]));
      }
    }
  }

  float4* o4 = (float4*)(hout + (size_t)node * DHID);
#pragma unroll
  for (int jc = 0; jc < 16; ++jc) {
    float4 v;
    v.x = acc[jc * 4 + 0]; v.y = acc[jc * 4 + 1];
    v.z = acc[jc * 4 + 2]; v.w = acc[jc * 4 + 3];
    if (do_relu) {
      v.x = fmaxf(v.x, 0.f); v.y = fmaxf(v.y, 0.f);
      v.z = fmaxf(v.z, 0.f); v.w = fmaxf(v.w, 0.f);
    }
    o4[jc] = v;
  }
}

// ---- Head: sort self-edges, logits, value, neighbors -----------------------

__global__ void k_head(const float* __restrict__ h, const int* __restrict__ dst,
                       const int* __restrict__ selfp, const int* __restrict__ selflist,
                       const int* __restrict__ selfcnt, const float* __restrict__ Wlog,
                       const float* __restrict__ blog, const float* __restrict__ Wval,
                       const float* __restrict__ bval, float* __restrict__ out) {
  __shared__ int sorted[SDEG];
  __shared__ int nbr[SDEG];
  int t = threadIdx.x;  // block = 64 threads (1 wave)
  int self = *selfp;
  if (t == 0) {
    int c = *selfcnt;
    if (c > SDEG) c = SDEG;
    int tmp[SDEG];
    for (int j = 0; j < SDEG; ++j) tmp[j] = (j < c) ? selflist[j] : 0;  // fill_value=0
    for (int a = 1; a < c; ++a) {  // insertion sort ascending (nonzero order)
      int v = tmp[a];
      int bq = a - 1;
      while (bq >= 0 && tmp[bq] > v) { tmp[bq + 1] = tmp[bq]; --bq; }
      tmp[bq + 1] = v;
    }
    for (int j = 0; j < SDEG; ++j) sorted[j] = tmp[j];
  }
  __syncthreads();
  if (t < SDEG) nbr[t] = dst[sorted[t]];
  __syncthreads();

  // logits: 16 rows x 128-dot; 4 lanes per row, 32 elems each
  int r = t >> 2, p = t & 3;
  float part = 0.f;
  for (int k = p * 32; k < p * 32 + 32; ++k) {
    float ev = (k < DHID) ? h[self * DHID + k] : h[nbr[r] * DHID + (k - DHID)];
    part += ev * Wlog[k];
  }
  part += __shfl_xor(part, 1);
  part += __shfl_xor(part, 2);
  if (p == 0) out[r] = part + blog[0];

  // value: self_emb . Wval
  float pv = h[self * DHID + t] * Wval[t];
#pragma unroll
  for (int off = 32; off; off >>= 1) pv += __shfl_xor(pv, off);
  if (t == 0) out[SDEG] = pv + bval[0];

  // neighbors as float
  if (t < SDEG) out[SDEG + 1 + t] = (float)nbr[t];
}

// ---- launcher --------------------------------------------------------------

extern "C" void kernel_launch(void* const* d_in, const int* in_sizes, int n_in,
                              void* d_out, int out_size, void* d_ws, size_t ws_size,
                              hipStream_t stream) {
  const float* x    = (const float*)d_in[0];
  const int*   ei   = (const int*)d_in[1];
  const int*   selfp= (const int*)d_in[2];
  const float* W0l  = (const float*)d_in[3];
  const float* W0r  = (const float*)d_in[4];
  const float* b0   = (const float*)d_in[5];
  const float* Wl   = (const float*)d_in[6];
  const float* Wr   = (const float*)d_in[7];
  const float* bb   = (const float*)d_in[8];
  const float* Wlog = (const float*)d_in[9];
  const float* blog = (const float*)d_in[10];
  const float* Wval = (const float*)d_in[11];
  const float* bval = (const float*)d_in[12];
  float* out = (float*)d_out;

  int N = in_sizes[0] / DIN;
  int E = in_sizes[1] / 2;
  const int* src = ei;
  const int* dstp = ei + E;

  size_t off = 0;
  auto alloc = [&](size_t bytes) {
    void* p = (char*)d_ws + off;
    off += (bytes + 255) & ~(size_t)255;
    return p;
  };
  int* meta    = (int*)alloc(64 * 4);           // [0]=gtotal [1]=selfcnt [2..17]=selflist
  int* deg     = (int*)alloc((size_t)N * 4);
  int* rowptr  = (int*)alloc((size_t)N * 4);
  int* cursor  = (int*)alloc((size_t)N * 4);
  int* col     = (int*)alloc((size_t)E * 4);
  float* hA    = (float*)alloc((size_t)N * DHID * 4);
  float* hB    = (float*)alloc((size_t)N * DHID * 4);
  float* mbuf  = (float*)alloc((size_t)N * DHID * 4);
  int* gtotal   = meta + 0;
  int* selfcnt  = meta + 1;
  int* selflist = meta + 2;

  hipMemsetAsync(meta, 0, 64 * 4, stream);
  hipMemsetAsync(deg, 0, (size_t)N * 4, stream);

  const int TB = 256;
  k_count<<<(E + TB - 1) / TB, TB, 0, stream>>>(dstp, deg, E);
  k_scan<<<(N + TB - 1) / TB, TB, 0, stream>>>(deg, rowptr, cursor, gtotal, N);
  k_fill<<<(E + TB - 1) / TB, TB, 0, stream>>>(src, dstp, cursor, col, selfp,
                                               selfcnt, selflist, E);

  k_layer0<<<2048, 256, 0, stream>>>(x, rowptr, deg, col, W0l, W0r, b0, hA, N);

  int mm_grid = (N + 255) / 256;
  // layer 1: hA -> hB (relu)
  k_agg<<<2048, 256, 0, stream>>>(hA, rowptr, deg, col, mbuf, N);
  k_mm<<<mm_grid, 256, 0, stream>>>(mbuf, hA, Wl + 0 * 4096, Wr + 0 * 4096,
                                    bb + 0 * 64, hB, N, 1);
  // layer 2: hB -> hA (relu)
  k_agg<<<2048, 256, 0, stream>>>(hB, rowptr, deg, col, mbuf, N);
  k_mm<<<mm_grid, 256, 0, stream>>>(mbuf, hB, Wl + 1 * 4096, Wr + 1 * 4096,
                                    bb + 1 * 64, hA, N, 1);
  // layer 3: hA -> hB (no relu)
  k_agg<<<2048, 256, 0, stream>>>(hA, rowptr, deg, col, mbuf, N);
  k_mm<<<mm_grid, 256, 0, stream>>>(mbuf, hA, Wl + 2 * 4096, Wr + 2 * 4096,
                                    bb + 2 * 64, hB, N, 0);

  k_head<<<1, 64, 0, stream>>>(hB, dstp, selfp, selflist, selfcnt, Wlog, blog,
                               Wval, bval, out);
}

// Round 4
// 672.970 us; speedup vs baseline: 1.6199x; 1.1017x over previous
//
#include <hip/hip_runtime.h>

#define DHID 64
#define DIN 6
#define SDEG 16
#define BSH 6                 // bucket = dst >> 6 (64 nodes/bucket)
#define NBMAX 2048            // LDS histogram capacity (NB = 1563 for N=100k)
#define CPAD 16               // bcursor padding (ints) to avoid line sharing

static __device__ __forceinline__ float rlane(float v, int k) {
  return __uint_as_float(__builtin_amdgcn_readlane(__float_as_uint(v), k));
}

// ---- CSR build: 2-level counting sort (locality-ordered scatter) -----------

__global__ __launch_bounds__(256) void k_bhist(const int* __restrict__ dst,
                                               int* __restrict__ bcount, int E, int NB) {
  __shared__ int h[NBMAX];
  for (int i = threadIdx.x; i < NB; i += 256) h[i] = 0;
  __syncthreads();
  for (int e = blockIdx.x * 256 + threadIdx.x; e < E; e += gridDim.x * 256)
    atomicAdd(&h[dst[e] >> BSH], 1);
  __syncthreads();
  for (int i = threadIdx.x; i < NB; i += 256) {
    int v = h[i];
    if (v) atomicAdd(&bcount[i], v);
  }
}

__global__ void k_bscan(const int* __restrict__ bcount, int* __restrict__ bbase,
                        int* __restrict__ bcursor, int NB) {
  int lane = threadIdx.x;  // single wave of 64
  int run = 0;
  for (int base = 0; base < NB; base += 64) {
    int i = base + lane;
    int d = (i < NB) ? bcount[i] : 0;
    int v = d;
#pragma unroll
    for (int off = 1; off < 64; off <<= 1) {
      int u = __shfl_up(v, off);
      if (lane >= off) v += u;
    }
    int excl = run + v - d;
    if (i < NB) { bbase[i] = excl; bcursor[i * CPAD] = excl; }
    run += __shfl(v, 63);
  }
  if (lane == 0) bbase[NB] = run;
}

__global__ __launch_bounds__(256) void k_bscatter(
    const int* __restrict__ src, const int* __restrict__ dst,
    int* __restrict__ bcursor, int* __restrict__ ebuf,
    const int* __restrict__ selfp, int* __restrict__ selfcnt,
    int* __restrict__ selflist, int E) {
  int e = blockIdx.x * 256 + threadIdx.x;
  if (e >= E) return;
  int s = src[e], d = dst[e];
  int pos = atomicAdd(&bcursor[(d >> BSH) * CPAD], 1);
  ebuf[pos] = (s << BSH) | (d & 63);          // src<<6 | dst_low6 (src < 2^26)
  if (s == *selfp) {
    int i = atomicAdd(selfcnt, 1);
    if (i < SDEG) selflist[i] = e;
  }
}

__global__ __launch_bounds__(256) void k_bfill(
    const int* __restrict__ ebuf, const int* __restrict__ bbase,
    int* __restrict__ rowptr, int* __restrict__ deg, int* __restrict__ col,
    int N) {
  __shared__ int cnt[64], cur[64];
  int b = blockIdx.x;
  int t = threadIdx.x;  // 256
  if (t < 64) cnt[t] = 0;
  __syncthreads();
  int lo = bbase[b], hi = bbase[b + 1];
  for (int i = lo + t; i < hi; i += 256) atomicAdd(&cnt[ebuf[i] & 63], 1);
  __syncthreads();
  if (t < 64) {  // one wave: exclusive scan of 64 counts
    int c = cnt[t];
    int v = c;
#pragma unroll
    for (int off = 1; off < 64; off <<= 1) {
      int u = __shfl_up(v, off);
      if (t >= off) v += u;
    }
    int start = lo + v - c;
    int node = (b << BSH) + t;
    if (node < N) { rowptr[node] = start; deg[node] = c; }
    cur[t] = start;
  }
  __syncthreads();
  for (int i = lo + t; i < hi; i += 256) {
    int p = ebuf[i];
    int pos = atomicAdd(&cur[p & 63], 1);
    col[pos] = p >> BSH;                      // writes land in ~4KB hot window
  }
}

// ---- Layer 0: x[N,6] -> h[N,64], ReLU --------------------------------------

__global__ __launch_bounds__(256) void k_layer0(
    const float* __restrict__ x, const int* __restrict__ rowptr,
    const int* __restrict__ deg, const int* __restrict__ col,
    const float* __restrict__ W0l, const float* __restrict__ W0r,
    const float* __restrict__ b0, float* __restrict__ hout, int N) {
  int lane = threadIdx.x & 63;
  int wid = blockIdx.x * (blockDim.x >> 6) + (threadIdx.x >> 6);
  int nw = gridDim.x * (blockDim.x >> 6);
  float w0l[DIN], w0r[DIN];
#pragma unroll
  for (int k = 0; k < DIN; ++k) {
    w0l[k] = W0l[k * DHID + lane];
    w0r[k] = W0r[k * DHID + lane];
  }
  float bv = b0[lane];
  int d6 = (lane < DIN) ? lane : 0;
  for (int node = wid; node < N; node += nw) {
    int start = rowptr[node], cnt = deg[node];
    float acc = 0.f;
    for (int e = 0; e < cnt; ++e) {
      int s = col[start + e];          // wave-uniform
      acc += x[s * DIN + d6];
    }
    float mean = acc / fmaxf((float)cnt, 1.0f);
    float xi = x[node * DIN + d6];
    float out = bv;
#pragma unroll
    for (int k = 0; k < DIN; ++k) {
      out = fmaf(rlane(mean, k), w0l[k], out);
      out = fmaf(rlane(xi, k), w0r[k], out);
    }
    hout[node * DHID + lane] = fmaxf(out, 0.f);
  }
}

// ---- Aggregation: mean[node][lane] = mean of h[src][lane] ------------------

__global__ __launch_bounds__(256) void k_agg(
    const float* __restrict__ hin, const int* __restrict__ rowptr,
    const int* __restrict__ deg, const int* __restrict__ col,
    float* __restrict__ mean, int N) {
  int lane = threadIdx.x & 63;
  int wid = blockIdx.x * (blockDim.x >> 6) + (threadIdx.x >> 6);
  int nw = gridDim.x * (blockDim.x >> 6);
  for (int node = wid; node < N; node += nw) {
    int start = rowptr[node], cnt = deg[node];
    float a0 = 0.f, a1 = 0.f, a2 = 0.f, a3 = 0.f;
    float a4 = 0.f, a5 = 0.f, a6 = 0.f, a7 = 0.f;
    int e = 0;
    for (; e + 8 <= cnt; e += 8) {
      int s0 = col[start + e + 0], s1 = col[start + e + 1];
      int s2 = col[start + e + 2], s3 = col[start + e + 3];
      int s4 = col[start + e + 4], s5 = col[start + e + 5];
      int s6 = col[start + e + 6], s7 = col[start + e + 7];
      a0 += hin[(size_t)s0 * DHID + lane];
      a1 += hin[(size_t)s1 * DHID + lane];
      a2 += hin[(size_t)s2 * DHID + lane];
      a3 += hin[(size_t)s3 * DHID + lane];
      a4 += hin[(size_t)s4 * DHID + lane];
      a5 += hin[(size_t)s5 * DHID + lane];
      a6 += hin[(size_t)s6 * DHID + lane];
      a7 += hin[(size_t)s7 * DHID + lane];
    }
    for (; e < cnt; ++e) a0 += hin[(size_t)col[start + e] * DHID + lane];
    float s = ((a0 + a1) + (a2 + a3)) + ((a4 + a5) + (a6 + a7));
    mean[(size_t)node * DHID + lane] = s / fmaxf((float)cnt, 1.0f);
  }
}

// ---- Transform: out = mean@Wl + h@Wr + b (optionally ReLU) -----------------

__global__ __launch_bounds__(256) void k_mm(
    const float* __restrict__ mean, const float* __restrict__ hin,
    const float* __restrict__ Wl, const float* __restrict__ Wr,
    const float* __restrict__ b, float* __restrict__ hout, int N, int do_relu) {
  __shared__ float4 sW[2064];  // [0..1023]=Wl rows, [1024..2047]=Wr, [2048..2063]=b
  int t = threadIdx.x;
  const float4* wl4 = (const float4*)Wl;
  const float4* wr4 = (const float4*)Wr;
  for (int i = t; i < 1024; i += 256) sW[i] = wl4[i];
  for (int i = t; i < 1024; i += 256) sW[1024 + i] = wr4[i];
  if (t < 16) sW[2048 + t] = ((const float4*)b)[t];
  __syncthreads();

  int node = blockIdx.x * 256 + t;
  if (node >= N) return;

  const float4* m4 = (const float4*)(mean + (size_t)node * DHID);
  const float4* h4 = (const float4*)(hin + (size_t)node * DHID);

  float acc[DHID];
#pragma unroll
  for (int jc = 0; jc < 16; ++jc) {
    float4 bv = sW[2048 + jc];
    acc[jc * 4 + 0] = bv.x; acc[jc * 4 + 1] = bv.y;
    acc[jc * 4 + 2] = bv.z; acc[jc * 4 + 3] = bv.w;
  }

  for (int kc = 0; kc < 16; ++kc) {
    float4 av = m4[kc];
    float4 hv = h4[kc];
#pragma unroll
    for (int kk = 0; kk < 4; ++kk) {
      int k = kc * 4 + kk;
      float a = (kk == 0) ? av.x : (kk == 1) ? av.y : (kk == 2) ? av.z : av.w;
      float hh = (kk == 0) ? hv.x : (kk == 1) ? hv.y : (kk == 2) ? hv.z : hv.w;
#pragma unroll
      for (int jc = 0; jc < 16; ++jc) {
        float4 wlv = sW[k * 16 + jc];
        float4 wrv = sW[1024 + k * 16 + jc];
        acc[jc * 4 + 0] = fmaf(a, wlv.x, fmaf(hh, wrv.x, acc[jc * 4 + 0]));
        acc[jc * 4 + 1] = fmaf(a, wlv.y, fmaf(hh, wrv.y, acc[jc * 4 + 1]));
        acc[jc * 4 + 2] = fmaf(a, wlv.z, fmaf(hh, wrv.z, acc[jc * 4 + 2]));
        acc[jc * 4 + 3] = fmaf(a, wlv.w, fmaf(hh, wrv.w, acc[jc * 4 + 3]));
      }
    }
  }

  float4* o4 = (float4*)(hout + (size_t)node * DHID);
#pragma unroll
  for (int jc = 0; jc < 16; ++jc) {
    float4 v;
    v.x = acc[jc * 4 + 0]; v.y = acc[jc * 4 + 1];
    v.z = acc[jc * 4 + 2]; v.w = acc[jc * 4 + 3];
    if (do_relu) {
      v.x = fmaxf(v.x, 0.f); v.y = fmaxf(v.y, 0.f);
      v.z = fmaxf(v.z, 0.f); v.w = fmaxf(v.w, 0.f);
    }
    o4[jc] = v;
  }
}

// ---- Head: sort self-edges, logits, value, neighbors -----------------------

__global__ void k_head(const float* __restrict__ h, const int* __restrict__ dst,
                       const int* __restrict__ selfp, const int* __restrict__ selflist,
                       const int* __restrict__ selfcnt, const float* __restrict__ Wlog,
                       const float* __restrict__ blog, const float* __restrict__ Wval,
                       const float* __restrict__ bval, float* __restrict__ out) {
  __shared__ int sorted[SDEG];
  __shared__ int nbr[SDEG];
  int t = threadIdx.x;  // block = 64 threads (1 wave)
  int self = *selfp;
  if (t == 0) {
    int c = *selfcnt;
    if (c > SDEG) c = SDEG;
    int tmp[SDEG];
    for (int j = 0; j < SDEG; ++j) tmp[j] = (j < c) ? selflist[j] : 0;
    for (int a = 1; a < c; ++a) {
      int v = tmp[a];
      int bq = a - 1;
      while (bq >= 0 && tmp[bq] > v) { tmp[bq + 1] = tmp[bq]; --bq; }
      tmp[bq + 1] = v;
    }
    for (int j = 0; j < SDEG; ++j) sorted[j] = tmp[j];
  }
  __syncthreads();
  if (t < SDEG) nbr[t] = dst[sorted[t]];
  __syncthreads();

  int r = t >> 2, p = t & 3;
  float part = 0.f;
  for (int k = p * 32; k < p * 32 + 32; ++k) {
    float ev = (k < DHID) ? h[self * DHID + k] : h[nbr[r] * DHID + (k - DHID)];
    part += ev * Wlog[k];
  }
  part += __shfl_xor(part, 1);
  part += __shfl_xor(part, 2);
  if (p == 0) out[r] = part + blog[0];

  float pv = h[self * DHID + t] * Wval[t];
#pragma unroll
  for (int off = 32; off; off >>= 1) pv += __shfl_xor(pv, off);
  if (t == 0) out[SDEG] = pv + bval[0];

  if (t < SDEG) out[SDEG + 1 + t] = (float)nbr[t];
}

// ---- launcher --------------------------------------------------------------

extern "C" void kernel_launch(void* const* d_in, const int* in_sizes, int n_in,
                              void* d_out, int out_size, void* d_ws, size_t ws_size,
                              hipStream_t stream) {
  const float* x    = (const float*)d_in[0];
  const int*   ei   = (const int*)d_in[1];
  const int*   selfp= (const int*)d_in[2];
  const float* W0l  = (const float*)d_in[3];
  const float* W0r  = (const float*)d_in[4];
  const float* b0   = (const float*)d_in[5];
  const float* Wl   = (const float*)d_in[6];
  const float* Wr   = (const float*)d_in[7];
  const float* bb   = (const float*)d_in[8];
  const float* Wlog = (const float*)d_in[9];
  const float* blog = (const float*)d_in[10];
  const float* Wval = (const float*)d_in[11];
  const float* bval = (const float*)d_in[12];
  float* out = (float*)d_out;

  int N = in_sizes[0] / DIN;
  int E = in_sizes[1] / 2;
  int NB = (N + 63) >> BSH;
  const int* src = ei;
  const int* dstp = ei + E;

  size_t off = 0;
  auto alloc = [&](size_t bytes) {
    void* p = (char*)d_ws + off;
    off += (bytes + 255) & ~(size_t)255;
    return p;
  };
  int* meta    = (int*)alloc(64 * 4);            // [0]=selfcnt [1..16]=selflist
  int* bcount  = (int*)alloc((size_t)NB * 4);
  int* bbase   = (int*)alloc((size_t)(NB + 1) * 4);
  int* bcursor = (int*)alloc((size_t)NB * CPAD * 4);
  int* ebuf    = (int*)alloc((size_t)E * 4);
  int* deg     = (int*)alloc((size_t)N * 4);
  int* rowptr  = (int*)alloc((size_t)N * 4);
  int* col     = (int*)alloc((size_t)E * 4);
  float* hA    = (float*)alloc((size_t)N * DHID * 4);
  float* hB    = (float*)alloc((size_t)N * DHID * 4);
  float* mbuf  = (float*)alloc((size_t)N * DHID * 4);
  int* selfcnt  = meta + 0;
  int* selflist = meta + 1;

  hipMemsetAsync(meta, 0, 64 * 4, stream);
  hipMemsetAsync(bcount, 0, (size_t)NB * 4, stream);

  const int TB = 256;
  k_bhist<<<256, TB, 0, stream>>>(dstp, bcount, E, NB);
  k_bscan<<<1, 64, 0, stream>>>(bcount, bbase, bcursor, NB);
  k_bscatter<<<(E + TB - 1) / TB, TB, 0, stream>>>(src, dstp, bcursor, ebuf,
                                                   selfp, selfcnt, selflist, E);
  k_bfill<<<NB, TB, 0, stream>>>(ebuf, bbase, rowptr, deg, col, N);

  k_layer0<<<2048, 256, 0, stream>>>(x, rowptr, deg, col, W0l, W0r, b0, hA, N);

  int mm_grid = (N + 255) / 256;
  k_agg<<<2048, 256, 0, stream>>>(hA, rowptr, deg, col, mbuf, N);
  k_mm<<<mm_grid, 256, 0, stream>>>(mbuf, hA, Wl + 0 * 4096, Wr + 0 * 4096,
                                    bb + 0 * 64, hB, N, 1);
  k_agg<<<2048, 256, 0, stream>>>(hB, rowptr, deg, col, mbuf, N);
  k_mm<<<mm_grid, 256, 0, stream>>>(mbuf, hB, Wl + 1 * 4096, Wr + 1 * 4096,
                                    bb + 1 * 64, hA, N, 1);
  k_agg<<<2048, 256, 0, stream>>>(hA, rowptr, deg, col, mbuf, N);
  k_mm<<<mm_grid, 256, 0, stream>>>(mbuf, hA, Wl + 2 * 4096, Wr + 2 * 4096,
                                    bb + 2 * 64, hB, N, 0);

  k_head<<<1, 64, 0, stream>>>(hB, dstp, selfp, selflist, selfcnt, Wlog, blog,
                               Wval, bval, out);
}